// Round 5
// baseline (413.585 us; speedup 1.0000x reference)
//
#include <hip/hip_runtime.h>

#define KG 20
#define N1 400
#define N2 760
#define BATCH 4096
#define NITER 50

typedef __attribute__((ext_vector_type(8))) short bf16x8;
typedef __attribute__((ext_vector_type(4))) float f32x4;
typedef __attribute__((ext_vector_type(2))) float f2;

// Pure compiler barrier: orders the LDS ops in the instruction stream but emits
// NO s_waitcnt. Intra-wave DS ops execute in program order; the compiler still
// auto-inserts lgkmcnt waits before read results are consumed.
#define CBAR() asm volatile("" ::: "memory")

__device__ __forceinline__ float bf2f(unsigned short u) {
    unsigned int x = ((unsigned int)u) << 16;
    union { unsigned int i; float f; } c; c.i = x; return c.f;
}
__device__ __forceinline__ unsigned short f2bf(float f) {
    union { float f; unsigned int i; } c; c.f = f;
    unsigned int r = c.i + 0x7FFFu + ((c.i >> 16) & 1u);  // RNE
    return (unsigned short)(r >> 16);
}
// HW packed f32->bf16 (RNE, same result as f2bf for finite values).
__device__ __forceinline__ unsigned pk_bf16(float lo, float hi) {
    unsigned r;
    asm("v_cvt_pk_bf16_f32 %0, %1, %2" : "=v"(r) : "v"(lo), "v"(hi));
    return r;
}

// packed helpers (elementwise; per-sample math identical to scalar version)
__device__ __forceinline__ f2 fabs2(f2 a) { a.x = __builtin_fabsf(a.x); a.y = __builtin_fabsf(a.y); return a; }
__device__ __forceinline__ f2 min0_2(f2 a) { a.x = fminf(a.x, 0.f); a.y = fminf(a.y, 0.f); return a; }

// ---------------- compile-time DCT-II tables -----------------------------------
constexpr double CPI = 3.14159265358979323846;
constexpr double ccos(double x) {
    constexpr double TP = 6.28318530717958647692;
    long long k = (long long)(x / TP);
    double r = x - (double)k * TP;
    if (r > CPI)  r -= TP;
    if (r < -CPI) r += TP;
    double r2 = r * r, term = 1.0, s = 1.0;
    for (int n = 1; n <= 15; ++n) { term *= -r2 / ((2.0 * n - 1.0) * (2.0 * n)); s += term; }
    return s;
}
struct Tbl { float phi[10][20]; float lam[20]; };   // rows 0..9 only (fold symmetry)
constexpr Tbl mk_tbl() {
    Tbl t{};
    for (int i = 0; i < 10; ++i)
        for (int a = 0; a < 20; ++a) {
            double na = (a == 0) ? 0.22360679774997896964 : 0.31622776601683793320;
            t.phi[i][a] = (float)(na * ccos(CPI * (double)a * ((double)i + 0.5) / 20.0));
        }
    for (int a = 0; a < 20; ++a) t.lam[a] = (float)(2.0 - 2.0 * ccos(CPI * (double)a / 20.0));
    return t;
}
static constexpr Tbl TB = mk_tbl();

__device__ __forceinline__ int detect_flag(const float* beqf) {
    float v = beqf[0];
    return (v > 0.5f && v < 1.5f) ? 0 : 1;   // 0 = fp32 inputs, 1 = bf16 inputs
}

// ---------------- input pre-conversion (fp32 path only does real work) ---------
__global__ __launch_bounds__(256) void cvt_inputs(
        const void* __restrict__ src0, const void* __restrict__ src1,
        unsigned short* __restrict__ dst0, unsigned short* __restrict__ dst1,
        const float* __restrict__ beqf) {
    const int f = detect_flag(beqf);
    const int nv0 = (4096 * 512) / 4, nv1 = (1024 * 512) / 4;
    int idx = blockIdx.x * 256 + threadIdx.x;          // vec4 index
    if (idx >= nv0 + nv1) return;
    const void* s; unsigned short* dptr; int k;
    if (idx < nv0) { s = src0; dptr = dst0; k = idx; }
    else           { s = src1; dptr = dst1; k = idx - nv0; }
    if (f) {
        ((uint2*)dptr)[k] = ((const uint2*)s)[k];      // already bf16: 8B copy
    } else {
        float4 v = ((const float4*)s)[k];
        uint2 p; p.x = pk_bf16(v.x, v.y); p.y = pk_bf16(v.z, v.w);
        ((uint2*)dptr)[k] = p;
    }
}

// ---------------- MLP GEMM: 128x64 block, software-pipelined K loop ------------
template<bool LEAKY>
__global__ __launch_bounds__(256) void gemm_bt_bf16(
        const unsigned short* __restrict__ A,
        const void* __restrict__ B,
        const void* __restrict__ biasRaw,
        unsigned short* __restrict__ C,
        int M, int N, int K, const float* __restrict__ beqf, int bUseFlag) {
    __shared__ unsigned short As[128 * 34];
    __shared__ unsigned short Bs[64 * 34];
    const int f   = detect_flag(beqf);
    const int bBf = bUseFlag ? f : 1;
    const int tid  = threadIdx.x;
    const int m0   = blockIdx.x * 128;
    const int n0   = blockIdx.y * 64;
    const int wave = tid >> 6, lane = tid & 63;
    const int wm   = (wave & 1) * 64, wn = (wave >> 1) * 32;
    const int fr   = lane & 15;
    const int kc   = (lane >> 4) * 8;

    const int ra = tid >> 1, ca = (tid & 1) * 16;
    const int rb = tid >> 2, cb = (tid & 3) * 8;
    const int rbg = (n0 + rb < N) ? (n0 + rb) : (N - 1);

    uint4 av0, av1, bv;
    auto load_tiles = [&](int k0) {
        size_t aoff = (size_t)(m0 + ra) * K + k0 + ca;
        av0 = *(const uint4*)&A[aoff];
        av1 = *(const uint4*)&A[aoff + 8];
        size_t boff = (size_t)rbg * K + k0 + cb;
        if (bBf) bv = *(const uint4*)&((const unsigned short*)B)[boff];
        else {
            const float* Bf = (const float*)B;
            float4 f0 = *(const float4*)&Bf[boff];
            float4 f1 = *(const float4*)&Bf[boff + 4];
            bv.x = pk_bf16(f0.x, f0.y);
            bv.y = pk_bf16(f0.z, f0.w);
            bv.z = pk_bf16(f1.x, f1.y);
            bv.w = pk_bf16(f1.z, f1.w);
        }
    };

    f32x4 acc[4][2];
#pragma unroll
    for (int a = 0; a < 4; a++)
#pragma unroll
        for (int b = 0; b < 2; b++) acc[a][b] = (f32x4){0.f, 0.f, 0.f, 0.f};

    load_tiles(0);
    for (int k0 = 0; k0 < K; k0 += 32) {
        *(uint4*)&As[ra * 34 + ca]     = av0;
        *(uint4*)&As[ra * 34 + ca + 8] = av1;
        *(uint4*)&Bs[rb * 34 + cb]     = bv;
        __syncthreads();

        int kn = (k0 + 32 < K) ? (k0 + 32) : k0;
        load_tiles(kn);

        bf16x8 af[4], bfm[2];
#pragma unroll
        for (int a = 0; a < 4; a++) af[a]  = *(const bf16x8*)&As[(wm + a * 16 + fr) * 34 + kc];
#pragma unroll
        for (int b = 0; b < 2; b++) bfm[b] = *(const bf16x8*)&Bs[(wn + b * 16 + fr) * 34 + kc];
#pragma unroll
        for (int a = 0; a < 4; a++)
#pragma unroll
            for (int b = 0; b < 2; b++)
                acc[a][b] = __builtin_amdgcn_mfma_f32_16x16x32_bf16(af[a], bfm[b], acc[a][b], 0, 0, 0);
        __syncthreads();
    }
#pragma unroll
    for (int a = 0; a < 4; a++)
#pragma unroll
        for (int b = 0; b < 2; b++) {
            int col = n0 + wn + b * 16 + (lane & 15);
            if (col < N) {
                float bs = f ? bf2f(((const unsigned short*)biasRaw)[col])
                             : ((const float*)biasRaw)[col];
#pragma unroll
                for (int r = 0; r < 4; r++) {
                    int row = m0 + wm + a * 16 + (lane >> 4) * 4 + r;
                    float v = acc[a][b][r] + bs;
                    if (LEAKY) v = v >= 0.f ? v : 0.1f * v;
                    C[(size_t)row * N + col] = f2bf(v);
                }
            }
        }
}

// ---------------- fused 50-iteration ADMM: 6 samples/wave, packed f32 ----------
// R5: the admm body is VALU-ISSUE-bound (wave64 = 2 issue-cyc/instr on SIMD-32;
// R1-R3 micro-probes all refuted). gfx950 has v_pk_{fma,add,mul}_f32 (VOP3P,
// 2 fp32 ops/issue) and LLVM selects them for <2 x float>. So: TWO samples per
// lane as f2 — every op becomes packed on independent samples; DCT constants
// are scalars broadcast across halves (loop-invariant, hoistable). Per-sample
// arithmetic is IEEE-identical to R4 -> bit-identical outputs. Blocks 1366->683
// (<=1 wave/SIMD everywhere; two in-lane sample streams hide LDS latency).
// launch_bounds(64,1): full 512-VGPR budget (expect ~300-400 live, <450 no-spill).
#define SREG 449    // f2 units; 3*449*8 = 10776 B; q-regions skewed by 2 banks
__global__ __launch_bounds__(64, 1) void admm_kernel(
        const unsigned short* __restrict__ wglob,
        void* __restrict__ out, const float* __restrict__ beqf) {
    __shared__ f2 buf[3 * SREG];

    const int lane = threadIdx.x;
    const int q    = (lane >= 40) ? 2 : (lane >= 20 ? 1 : 0);
    const int i    = lane - 20 * q;
    const int s0   = blockIdx.x * 6 + q * 2;      // this lane's sample pair: s0, s0+1
    const int flag = detect_flag(beqf);

    if (lane < 60 && s0 < BATCH) {                // BATCH even -> s0 valid => s0+1 valid
        f2*    B2 = &buf[q * SREG];
        float* Bf = (float*)B2;
        const size_t gb0 = (size_t)s0 * N2;
        const size_t gb1 = gb0 + N2;

        f2 wh[20], wv[20];
        if (i < 19) {
#pragma unroll
            for (int j = 0; j < 19; ++j) {
                wh[j].x = bf2f(wglob[gb0 + 39 * i + 2 * j]);
                wh[j].y = bf2f(wglob[gb1 + 39 * i + 2 * j]);
                wv[j].x = bf2f(wglob[gb0 + 39 * i + 2 * j + 1]);
                wv[j].y = bf2f(wglob[gb1 + 39 * i + 2 * j + 1]);
            }
            wh[19] = (f2)0.f;
            wv[19].x = bf2f(wglob[gb0 + 39 * i + 38]);
            wv[19].y = bf2f(wglob[gb1 + 39 * i + 38]);
        } else {
#pragma unroll
            for (int j = 0; j < 19; ++j) {
                wh[j].x = bf2f(wglob[gb0 + 741 + j]);
                wh[j].y = bf2f(wglob[gb1 + 741 + j]);
                wv[j] = (f2)0.f;
            }
            wh[19] = (f2)0.f; wv[19] = (f2)0.f;
        }

        float g[20];
        {
            float lamB = TB.lam[i];
#pragma unroll
            for (int a = 0; a < 20; ++a) g[a] = 1.f / (TB.lam[a] + lamB);
            if (i == 0) g[0] = 0.f;   // zero mode (0,0)
        }

        f2 sh[20], sv[20];
#pragma unroll
        for (int j = 0; j < 20; ++j) { sh[j] = (f2)0.f; sv[j] = (f2)0.f; }

        const int rup = (i > 0)  ? i - 1 : 0;
        const int rdn = (i < 19) ? i + 1 : i;
        const float two0  = (i == 0)  ? 2.f : 0.f;
        const float two19 = (i == 19) ? 2.f : 0.f;

#pragma unroll 1
        for (int it = 0; it < NITER; ++it) {
            f2 vh[20], vv[20];
#pragma unroll
            for (int j = 0; j < 20; ++j) {
                vh[j] = fabs2(sh[j]) - wh[j];
                vv[j] = fabs2(sv[j]) - wv[j];
            }
            // ---- vv exchange (row i-1), stride 20 f2, b128 ops ----
#pragma unroll
            for (int j = 0; j < 20; j += 2) {
                f32x4 t; t[0] = vv[j].x; t[1] = vv[j].y; t[2] = vv[j + 1].x; t[3] = vv[j + 1].y;
                *(f32x4*)&Bf[(20 * i + j) * 2] = t;
            }
            CBAR();
            f2 vvUp[20];
#pragma unroll
            for (int j = 0; j < 20; j += 2) {
                f32x4 t = *(const f32x4*)&Bf[(20 * rup + j) * 2];
                vvUp[j].x = t[0]; vvUp[j].y = t[1]; vvUp[j + 1].x = t[2]; vvUp[j + 1].y = t[3];
            }
            CBAR();
            f2 r[20];
#pragma unroll
            for (int j = 0; j < 20; ++j) {
                f2 acc = ((j < 19) ? vh[j] : (f2)0.f) + vv[j];
                if (j > 0) acc -= vh[j - 1];
                if (i > 0) acc -= vvUp[j];
                r[j] = acc;
            }
            r[0]  -= two0;
            r[19] += two19;

            // ---- fold rows ----
            f2 e[10], o[10];
#pragma unroll
            for (int jj = 0; jj < 10; ++jj) { e[jj] = r[jj] + r[19 - jj]; o[jj] = r[jj] - r[19 - jj]; }
            // ---- T1[b] = folded row-DCT; transpose-1 store (stride 22, b64) ----
#pragma unroll
            for (int b = 0; b < 20; ++b) {
                f2 a;
                if ((b & 1) == 0) {
                    a = e[0] * TB.phi[0][b];
#pragma unroll
                    for (int jj = 1; jj < 10; ++jj) a += e[jj] * TB.phi[jj][b];
                } else {
                    a = o[0] * TB.phi[0][b];
#pragma unroll
                    for (int jj = 1; jj < 10; ++jj) a += o[jj] * TB.phi[jj][b];
                }
                B2[22 * b + i] = a;
            }
            CBAR();
            f2 t2[20];
#pragma unroll
            for (int k = 0; k < 20; k += 2) {
                f32x4 t = *(const f32x4*)&Bf[(22 * i + k) * 2];
                t2[k].x = t[0]; t2[k].y = t[1]; t2[k + 1].x = t[2]; t2[k + 1].y = t[3];
            }
            CBAR();
            // ---- fold; U[a] = col-DCT; scale by g ----
            f2 e2[10], o2[10];
#pragma unroll
            for (int kk = 0; kk < 10; ++kk) { e2[kk] = t2[kk] + t2[19 - kk]; o2[kk] = t2[kk] - t2[19 - kk]; }
            f2 v2[20];
#pragma unroll
            for (int a = 0; a < 20; ++a) {
                f2 acc;
                if ((a & 1) == 0) {
                    acc = e2[0] * TB.phi[0][a];
#pragma unroll
                    for (int kk = 1; kk < 10; ++kk) acc += e2[kk] * TB.phi[kk][a];
                } else {
                    acc = o2[0] * TB.phi[0][a];
#pragma unroll
                    for (int kk = 1; kk < 10; ++kk) acc += o2[kk] * TB.phi[kk][a];
                }
                v2[a] = acc * g[a];
            }
            // ---- Y rows (output-pair folded); transpose-2 store (b64) ----
#pragma unroll
            for (int II = 0; II < 10; ++II) {
                f2 E = v2[0] * TB.phi[II][0];
#pragma unroll
                for (int m = 1; m < 10; ++m) E += v2[2 * m] * TB.phi[II][2 * m];
                f2 O = v2[1] * TB.phi[II][1];
#pragma unroll
                for (int m = 1; m < 10; ++m) O += v2[2 * m + 1] * TB.phi[II][2 * m + 1];
                B2[22 * II + i]        = E + O;
                B2[22 * (19 - II) + i] = E - O;
            }
            CBAR();
            f2 t3[20];
#pragma unroll
            for (int b = 0; b < 20; b += 2) {
                f32x4 t = *(const f32x4*)&Bf[(22 * i + b) * 2];
                t3[b].x = t[0]; t3[b].y = t[1]; t3[b + 1].x = t[2]; t3[b + 1].y = t[3];
            }
            CBAR();
            // ---- nu rows (output-pair folded) ----
            f2 nu[20];
#pragma unroll
            for (int JJ = 0; JJ < 10; ++JJ) {
                f2 E = t3[0] * TB.phi[JJ][0];
#pragma unroll
                for (int m = 1; m < 10; ++m) E += t3[2 * m] * TB.phi[JJ][2 * m];
                f2 O = t3[1] * TB.phi[JJ][1];
#pragma unroll
                for (int m = 1; m < 10; ++m) O += t3[2 * m + 1] * TB.phi[JJ][2 * m + 1];
                nu[JJ]      = E + O;
                nu[19 - JJ] = E - O;
            }
            // ---- nu exchange (row i+1) ----
#pragma unroll
            for (int j = 0; j < 20; j += 2) {
                f32x4 t; t[0] = nu[j].x; t[1] = nu[j].y; t[2] = nu[j + 1].x; t[3] = nu[j + 1].y;
                *(f32x4*)&Bf[(20 * i + j) * 2] = t;
            }
            CBAR();
            f2 nuDn[20];
#pragma unroll
            for (int j = 0; j < 20; j += 2) {
                f32x4 t = *(const f32x4*)&Bf[(20 * rdn + j) * 2];
                nuDn[j].x = t[0]; nuDn[j].y = t[1]; nuDn[j + 1].x = t[2]; nuDn[j + 1].y = t[3];
            }
            CBAR();
#pragma unroll
            for (int j = 0; j < 20; ++j) {
                f2 xv = 0.5f * (vv[j] - nu[j] + nuDn[j]);
                sv[j] = xv + min0_2(sv[j]);
                f2 xh = (f2)0.f;
                if (j < 19) {
                    xh = 0.5f * (vh[j] - nu[j] + nu[j + 1]);
                    sh[j] = xh + min0_2(sh[j]);
                }
                if (it == NITER - 1) {
                    if (i < 19) {
                        if (j < 19) {
                            if (flag) {
                                ((unsigned short*)out)[gb0 + 39 * i + 2 * j]     = f2bf(xh.x);
                                ((unsigned short*)out)[gb0 + 39 * i + 2 * j + 1] = f2bf(xv.x);
                                ((unsigned short*)out)[gb1 + 39 * i + 2 * j]     = f2bf(xh.y);
                                ((unsigned short*)out)[gb1 + 39 * i + 2 * j + 1] = f2bf(xv.y);
                            } else {
                                ((float*)out)[gb0 + 39 * i + 2 * j]     = xh.x;
                                ((float*)out)[gb0 + 39 * i + 2 * j + 1] = xv.x;
                                ((float*)out)[gb1 + 39 * i + 2 * j]     = xh.y;
                                ((float*)out)[gb1 + 39 * i + 2 * j + 1] = xv.y;
                            }
                        } else {
                            if (flag) {
                                ((unsigned short*)out)[gb0 + 39 * i + 38] = f2bf(xv.x);
                                ((unsigned short*)out)[gb1 + 39 * i + 38] = f2bf(xv.y);
                            } else {
                                ((float*)out)[gb0 + 39 * i + 38] = xv.x;
                                ((float*)out)[gb1 + 39 * i + 38] = xv.y;
                            }
                        }
                    } else if (j < 19) {
                        if (flag) {
                            ((unsigned short*)out)[gb0 + 741 + j] = f2bf(xh.x);
                            ((unsigned short*)out)[gb1 + 741 + j] = f2bf(xh.y);
                        } else {
                            ((float*)out)[gb0 + 741 + j] = xh.x;
                            ((float*)out)[gb1 + 741 + j] = xh.y;
                        }
                    }
                }
            }
        }
    }
}

extern "C" void kernel_launch(void* const* d_in, const int* in_sizes, int n_in,
                              void* d_out, int out_size, void* d_ws, size_t ws_size,
                              hipStream_t stream) {
    (void)in_sizes; (void)n_in; (void)out_size; (void)ws_size;
    const void*  d   = d_in[0];
    const void*  W1  = d_in[1];
    const void*  b1  = d_in[2];
    const void*  W2  = d_in[3];
    const void*  b2  = d_in[4];
    const float* beq = (const float*)d_in[6];   // A (d_in[5]) unused: closed-form

    char* ws = (char*)d_ws;
    // Layout (total 14614528 B):
    //   h_bf  @ 0        : 4096x1024 bf16 = 8388608 B   (gemm1 out, gemm2 in)
    //   w_bf  @ 8388608  : 4096x760  bf16 = 6225920 B   (gemm2 out, admm in)
    //   d_bf  @ 8388608  : 4096x512  bf16 = 4194304 B   (aliases w_bf: dead
    //   w1_bf @ 12582912 : 1024x512  bf16 = 1048576 B    by the time gemm2
    //                                                    overwrites w_bf)
    unsigned short* h_bf  = (unsigned short*)(ws);
    unsigned short* w_bf  = (unsigned short*)(ws + 8388608);
    unsigned short* d_bf  = (unsigned short*)(ws + 8388608);
    unsigned short* w1_bf = (unsigned short*)(ws + 12582912);

    cvt_inputs<<<2560, 256, 0, stream>>>(d, W1, d_bf, w1_bf, beq);

    gemm_bt_bf16<true ><<<dim3(32, 16), 256, 0, stream>>>(d_bf, w1_bf, b1, h_bf, 4096, 1024, 512,  beq, 0);
    gemm_bt_bf16<false><<<dim3(32, 12), 256, 0, stream>>>(h_bf, W2,    b2, w_bf, 4096, 760,  1024, beq, 1);

    admm_kernel<<<(BATCH + 5) / 6, 64, 0, stream>>>(w_bf, d_out, beq);
}

// Round 6
// 337.041 us; speedup vs baseline: 1.2271x; 1.2271x over previous
//
#include <hip/hip_runtime.h>

#define KG 20
#define N1 400
#define N2 760
#define BATCH 4096
#define NITER 50

typedef __attribute__((ext_vector_type(8))) short bf16x8;
typedef __attribute__((ext_vector_type(4))) float f32x4;

// Pure compiler barrier: orders the LDS ops in the instruction stream but emits
// NO s_waitcnt. Intra-wave DS ops execute in program order; the compiler still
// auto-inserts lgkmcnt waits before read results are consumed.
#define CBAR() asm volatile("" ::: "memory")

__device__ __forceinline__ float bf2f(unsigned short u) {
    unsigned int x = ((unsigned int)u) << 16;
    union { unsigned int i; float f; } c; c.i = x; return c.f;
}
__device__ __forceinline__ unsigned short f2bf(float f) {
    union { float f; unsigned int i; } c; c.f = f;
    unsigned int r = c.i + 0x7FFFu + ((c.i >> 16) & 1u);  // RNE
    return (unsigned short)(r >> 16);
}
// HW packed f32->bf16 (RNE, same result as f2bf for finite values).
__device__ __forceinline__ unsigned pk_bf16(float lo, float hi) {
    unsigned r;
    asm("v_cvt_pk_bf16_f32 %0, %1, %2" : "=v"(r) : "v"(lo), "v"(hi));
    return r;
}

// ---------------- compile-time DCT-II tables -----------------------------------
constexpr double CPI = 3.14159265358979323846;
constexpr double ccos(double x) {
    constexpr double TP = 6.28318530717958647692;
    long long k = (long long)(x / TP);
    double r = x - (double)k * TP;
    if (r > CPI)  r -= TP;
    if (r < -CPI) r += TP;
    double r2 = r * r, term = 1.0, s = 1.0;
    for (int n = 1; n <= 15; ++n) { term *= -r2 / ((2.0 * n - 1.0) * (2.0 * n)); s += term; }
    return s;
}
struct Tbl { float phi[10][20]; float lam[20]; };   // rows 0..9 only (fold symmetry)
constexpr Tbl mk_tbl() {
    Tbl t{};
    for (int i = 0; i < 10; ++i)
        for (int a = 0; a < 20; ++a) {
            double na = (a == 0) ? 0.22360679774997896964 : 0.31622776601683793320;
            t.phi[i][a] = (float)(na * ccos(CPI * (double)a * ((double)i + 0.5) / 20.0));
        }
    for (int a = 0; a < 20; ++a) t.lam[a] = (float)(2.0 - 2.0 * ccos(CPI * (double)a / 20.0));
    return t;
}
static constexpr Tbl TB = mk_tbl();

__device__ __forceinline__ int detect_flag(const float* beqf) {
    float v = beqf[0];
    return (v > 0.5f && v < 1.5f) ? 0 : 1;   // 0 = fp32 inputs, 1 = bf16 inputs
}

// ---------------- input pre-conversion (fp32 path only does real work) ---------
__global__ __launch_bounds__(256) void cvt_inputs(
        const void* __restrict__ src0, const void* __restrict__ src1,
        unsigned short* __restrict__ dst0, unsigned short* __restrict__ dst1,
        const float* __restrict__ beqf) {
    const int f = detect_flag(beqf);
    const int nv0 = (4096 * 512) / 4, nv1 = (1024 * 512) / 4;
    int idx = blockIdx.x * 256 + threadIdx.x;          // vec4 index
    if (idx >= nv0 + nv1) return;
    const void* s; unsigned short* dptr; int k;
    if (idx < nv0) { s = src0; dptr = dst0; k = idx; }
    else           { s = src1; dptr = dst1; k = idx - nv0; }
    if (f) {
        ((uint2*)dptr)[k] = ((const uint2*)s)[k];      // already bf16: 8B copy
    } else {
        float4 v = ((const float4*)s)[k];
        uint2 p; p.x = pk_bf16(v.x, v.y); p.y = pk_bf16(v.z, v.w);
        ((uint2*)dptr)[k] = p;
    }
}

// ---------------- MLP GEMM: 128x128 block (R6: was 128x64) ---------------------
// R6 theory: non-admm ~96us is A-slab HBM re-fetch (each n-block refetches the
// A rows; 128x64 tiles -> ~240MB total traffic ~ 38us floor + poor L2 reuse).
// 128x128 tile halves the n-block count -> ~128MB. m97 geometry: 4 waves 2x2,
// acc[4][4], LDS 2x128x34 shorts = 17.4KB.
template<bool LEAKY>
__global__ __launch_bounds__(256) void gemm_bt_bf16(
        const unsigned short* __restrict__ A,
        const void* __restrict__ B,
        const void* __restrict__ biasRaw,
        unsigned short* __restrict__ C,
        int M, int N, int K, const float* __restrict__ beqf, int bUseFlag) {
    __shared__ unsigned short As[128 * 34];
    __shared__ unsigned short Bs[128 * 34];
    const int f   = detect_flag(beqf);
    const int bBf = bUseFlag ? f : 1;
    const int tid  = threadIdx.x;
    const int m0   = blockIdx.x * 128;
    const int n0   = blockIdx.y * 128;
    const int wave = tid >> 6, lane = tid & 63;
    const int wm   = (wave & 1) * 64, wn = (wave >> 1) * 64;
    const int fr   = lane & 15;
    const int kc   = (lane >> 4) * 8;

    const int ra = tid >> 1, ca = (tid & 1) * 16;      // A: 128 rows x 32 cols
    const int rb = tid >> 1, cb = (tid & 1) * 16;      // B: 128 rows x 32 cols
    const int rbg = (n0 + rb < N) ? (n0 + rb) : (N - 1);

    uint4 av0, av1, bv0, bv1;
    auto load_tiles = [&](int k0) {
        size_t aoff = (size_t)(m0 + ra) * K + k0 + ca;
        av0 = *(const uint4*)&A[aoff];
        av1 = *(const uint4*)&A[aoff + 8];
        size_t boff = (size_t)rbg * K + k0 + cb;
        if (bBf) {
            bv0 = *(const uint4*)&((const unsigned short*)B)[boff];
            bv1 = *(const uint4*)&((const unsigned short*)B)[boff + 8];
        } else {
            const float* Bf = (const float*)B;
            float4 f0 = *(const float4*)&Bf[boff];
            float4 f1 = *(const float4*)&Bf[boff + 4];
            float4 f2 = *(const float4*)&Bf[boff + 8];
            float4 f3 = *(const float4*)&Bf[boff + 12];
            bv0.x = pk_bf16(f0.x, f0.y);
            bv0.y = pk_bf16(f0.z, f0.w);
            bv0.z = pk_bf16(f1.x, f1.y);
            bv0.w = pk_bf16(f1.z, f1.w);
            bv1.x = pk_bf16(f2.x, f2.y);
            bv1.y = pk_bf16(f2.z, f2.w);
            bv1.z = pk_bf16(f3.x, f3.y);
            bv1.w = pk_bf16(f3.z, f3.w);
        }
    };

    f32x4 acc[4][4];
#pragma unroll
    for (int a = 0; a < 4; a++)
#pragma unroll
        for (int b = 0; b < 4; b++) acc[a][b] = (f32x4){0.f, 0.f, 0.f, 0.f};

    load_tiles(0);
    for (int k0 = 0; k0 < K; k0 += 32) {
        *(uint4*)&As[ra * 34 + ca]     = av0;
        *(uint4*)&As[ra * 34 + ca + 8] = av1;
        *(uint4*)&Bs[rb * 34 + cb]     = bv0;
        *(uint4*)&Bs[rb * 34 + cb + 8] = bv1;
        __syncthreads();

        int kn = (k0 + 32 < K) ? (k0 + 32) : k0;
        load_tiles(kn);

        bf16x8 af[4], bfm[4];
#pragma unroll
        for (int a = 0; a < 4; a++) af[a]  = *(const bf16x8*)&As[(wm + a * 16 + fr) * 34 + kc];
#pragma unroll
        for (int b = 0; b < 4; b++) bfm[b] = *(const bf16x8*)&Bs[(wn + b * 16 + fr) * 34 + kc];
#pragma unroll
        for (int a = 0; a < 4; a++)
#pragma unroll
            for (int b = 0; b < 4; b++)
                acc[a][b] = __builtin_amdgcn_mfma_f32_16x16x32_bf16(af[a], bfm[b], acc[a][b], 0, 0, 0);
        __syncthreads();
    }
#pragma unroll
    for (int a = 0; a < 4; a++)
#pragma unroll
        for (int b = 0; b < 4; b++) {
            int col = n0 + wn + b * 16 + (lane & 15);
            if (col < N) {
                float bs = f ? bf2f(((const unsigned short*)biasRaw)[col])
                             : ((const float*)biasRaw)[col];
#pragma unroll
                for (int r = 0; r < 4; r++) {
                    int row = m0 + wm + a * 16 + (lane >> 4) * 4 + r;
                    float v = acc[a][b][r] + bs;
                    if (LEAKY) v = v >= 0.f ? v : 0.1f * v;
                    C[(size_t)row * N + col] = f2bf(v);
                }
            }
        }
}

// ---------------- fused 50-iteration ADMM: 3 samples/wave (R4-exact, FROZEN) ---
// 5 rounds of probes (shfl, VGPR pin, SGPR pin, f2 packing) all regressed or
// were neutral. This structure's equilibrium: per-wave issue ~242k cyc; the
// 342 doubly-loaded SIMDs run ~484k cyc issue-bound; stalls hidden by the
// co-resident wave. f2 packing cut issue/sample 35% but dropped wave count to
// 683 (1/SIMD) exposing ~436k stall cyc/wave -> net loss (R5). Do not touch.
#define SREG 448
__global__ __launch_bounds__(64, 1) void admm_kernel(
        const unsigned short* __restrict__ wglob,
        void* __restrict__ out, const float* __restrict__ beqf) {
    __shared__ float buf[3 * SREG];                // 5376 B

    const int lane = threadIdx.x;
    const int q    = (lane >= 40) ? 2 : (lane >= 20 ? 1 : 0);
    const int i    = lane - 20 * q;
    const int sample = blockIdx.x * 3 + q;
    const int flag = detect_flag(beqf);

    if (lane < 60 && sample < BATCH) {
        float* B = &buf[q * SREG];
        const size_t gb = (size_t)sample * N2;

        float wh[20], wv[20];
        if (i < 19) {
#pragma unroll
            for (int j = 0; j < 19; ++j) {
                wh[j] = bf2f(wglob[gb + 39 * i + 2 * j]);
                wv[j] = bf2f(wglob[gb + 39 * i + 2 * j + 1]);
            }
            wh[19] = 0.f;
            wv[19] = bf2f(wglob[gb + 39 * i + 38]);
        } else {
#pragma unroll
            for (int j = 0; j < 19; ++j) { wh[j] = bf2f(wglob[gb + 741 + j]); wv[j] = 0.f; }
            wh[19] = 0.f; wv[19] = 0.f;
        }

        float g[20];
        {
            float lamB = TB.lam[i];
#pragma unroll
            for (int a = 0; a < 20; ++a) g[a] = 1.f / (TB.lam[a] + lamB);
            if (i == 0) g[0] = 0.f;   // zero mode (0,0)
        }

        float sh[20], sv[20];
#pragma unroll
        for (int j = 0; j < 20; ++j) { sh[j] = 0.f; sv[j] = 0.f; }

        const int rup = (i > 0)  ? i - 1 : 0;
        const int rdn = (i < 19) ? i + 1 : i;

#pragma unroll 1
        for (int it = 0; it < NITER; ++it) {
            float vh[20], vv[20];
#pragma unroll
            for (int j = 0; j < 20; ++j) {
                vh[j] = fabsf(sh[j]) - wh[j];
                vv[j] = fabsf(sv[j]) - wv[j];
            }
#pragma unroll
            for (int j = 0; j < 20; j += 4)
                *(f32x4*)&B[20 * i + j] = (f32x4){vv[j], vv[j + 1], vv[j + 2], vv[j + 3]};
            CBAR();
            float vvUp[20];
#pragma unroll
            for (int j = 0; j < 20; j += 4) {
                f32x4 t = *(f32x4*)&B[20 * rup + j];
                vvUp[j] = t[0]; vvUp[j + 1] = t[1]; vvUp[j + 2] = t[2]; vvUp[j + 3] = t[3];
            }
            CBAR();
            float r[20];
#pragma unroll
            for (int j = 0; j < 20; ++j) {
                float acc = ((j < 19) ? vh[j] : 0.f) + vv[j];
                if (j > 0) acc -= vh[j - 1];
                acc -= (i > 0) ? vvUp[j] : 0.f;
                r[j] = acc;
            }
            r[0]  -= (i == 0)  ? 2.f : 0.f;
            r[19] += (i == 19) ? 2.f : 0.f;

            // ---- fold rows ----
            float e[10], o[10];
#pragma unroll
            for (int jj = 0; jj < 10; ++jj) { e[jj] = r[jj] + r[19 - jj]; o[jj] = r[jj] - r[19 - jj]; }
            // ---- T1[b] = folded row-DCT; transpose-1 store (stride 22) ----
#pragma unroll
            for (int b = 0; b < 20; ++b) {
                float a;
                if ((b & 1) == 0) {
                    a = e[0] * TB.phi[0][b];
#pragma unroll
                    for (int jj = 1; jj < 10; ++jj) a += e[jj] * TB.phi[jj][b];
                } else {
                    a = o[0] * TB.phi[0][b];
#pragma unroll
                    for (int jj = 1; jj < 10; ++jj) a += o[jj] * TB.phi[jj][b];
                }
                B[22 * b + i] = a;
            }
            CBAR();
            float t2[20];
#pragma unroll
            for (int k = 0; k < 20; k += 2) {
                float2 p = *(const float2*)&B[22 * i + k];
                t2[k] = p.x; t2[k + 1] = p.y;
            }
            CBAR();
            // ---- fold; U[a] = col-DCT; scale by g ----
            float e2[10], o2[10];
#pragma unroll
            for (int kk = 0; kk < 10; ++kk) { e2[kk] = t2[kk] + t2[19 - kk]; o2[kk] = t2[kk] - t2[19 - kk]; }
            float v2[20];
#pragma unroll
            for (int a = 0; a < 20; ++a) {
                float acc;
                if ((a & 1) == 0) {
                    acc = e2[0] * TB.phi[0][a];
#pragma unroll
                    for (int kk = 1; kk < 10; ++kk) acc += e2[kk] * TB.phi[kk][a];
                } else {
                    acc = o2[0] * TB.phi[0][a];
#pragma unroll
                    for (int kk = 1; kk < 10; ++kk) acc += o2[kk] * TB.phi[kk][a];
                }
                v2[a] = acc * g[a];
            }
            // ---- Y rows (output-pair folded); transpose-2 store ----
#pragma unroll
            for (int II = 0; II < 10; ++II) {
                float E = v2[0] * TB.phi[II][0];
#pragma unroll
                for (int m = 1; m < 10; ++m) E += v2[2 * m] * TB.phi[II][2 * m];
                float O = v2[1] * TB.phi[II][1];
#pragma unroll
                for (int m = 1; m < 10; ++m) O += v2[2 * m + 1] * TB.phi[II][2 * m + 1];
                B[22 * II + i]        = E + O;
                B[22 * (19 - II) + i] = E - O;
            }
            CBAR();
            float t3[20];
#pragma unroll
            for (int b = 0; b < 20; b += 2) {
                float2 p = *(const float2*)&B[22 * i + b];
                t3[b] = p.x; t3[b + 1] = p.y;
            }
            CBAR();
            // ---- nu rows (output-pair folded) ----
            float nu[20];
#pragma unroll
            for (int JJ = 0; JJ < 10; ++JJ) {
                float E = t3[0] * TB.phi[JJ][0];
#pragma unroll
                for (int m = 1; m < 10; ++m) E += t3[2 * m] * TB.phi[JJ][2 * m];
                float O = t3[1] * TB.phi[JJ][1];
#pragma unroll
                for (int m = 1; m < 10; ++m) O += t3[2 * m + 1] * TB.phi[JJ][2 * m + 1];
                nu[JJ]      = E + O;
                nu[19 - JJ] = E - O;
            }
#pragma unroll
            for (int j = 0; j < 20; j += 4)
                *(f32x4*)&B[20 * i + j] = (f32x4){nu[j], nu[j + 1], nu[j + 2], nu[j + 3]};
            CBAR();
            float nuDn[20];
#pragma unroll
            for (int j = 0; j < 20; j += 4) {
                f32x4 t = *(f32x4*)&B[20 * rdn + j];
                nuDn[j] = t[0]; nuDn[j + 1] = t[1]; nuDn[j + 2] = t[2]; nuDn[j + 3] = t[3];
            }
            CBAR();
#pragma unroll
            for (int j = 0; j < 20; ++j) {
                float xv = 0.5f * (vv[j] - nu[j] + nuDn[j]);
                sv[j] = xv + fminf(sv[j], 0.f);
                float xh = 0.f;
                if (j < 19) {
                    xh = 0.5f * (vh[j] - nu[j] + nu[j + 1]);
                    sh[j] = xh + fminf(sh[j], 0.f);
                }
                if (it == NITER - 1) {
                    if (i < 19) {
                        if (j < 19) {
                            if (flag) {
                                ((unsigned short*)out)[gb + 39 * i + 2 * j]     = f2bf(xh);
                                ((unsigned short*)out)[gb + 39 * i + 2 * j + 1] = f2bf(xv);
                            } else {
                                ((float*)out)[gb + 39 * i + 2 * j]     = xh;
                                ((float*)out)[gb + 39 * i + 2 * j + 1] = xv;
                            }
                        } else {
                            if (flag) ((unsigned short*)out)[gb + 39 * i + 38] = f2bf(xv);
                            else      ((float*)out)[gb + 39 * i + 38] = xv;
                        }
                    } else if (j < 19) {
                        if (flag) ((unsigned short*)out)[gb + 741 + j] = f2bf(xh);
                        else      ((float*)out)[gb + 741 + j] = xh;
                    }
                }
            }
        }
    }
}

extern "C" void kernel_launch(void* const* d_in, const int* in_sizes, int n_in,
                              void* d_out, int out_size, void* d_ws, size_t ws_size,
                              hipStream_t stream) {
    (void)in_sizes; (void)n_in; (void)out_size; (void)ws_size;
    const void*  d   = d_in[0];
    const void*  W1  = d_in[1];
    const void*  b1  = d_in[2];
    const void*  W2  = d_in[3];
    const void*  b2  = d_in[4];
    const float* beq = (const float*)d_in[6];   // A (d_in[5]) unused: closed-form

    char* ws = (char*)d_ws;
    // Layout (total 14614528 B):
    //   h_bf  @ 0        : 4096x1024 bf16 = 8388608 B   (gemm1 out, gemm2 in)
    //   w_bf  @ 8388608  : 4096x760  bf16 = 6225920 B   (gemm2 out, admm in)
    //   d_bf  @ 8388608  : 4096x512  bf16 = 4194304 B   (aliases w_bf: dead
    //   w1_bf @ 12582912 : 1024x512  bf16 = 1048576 B    by the time gemm2
    //                                                    overwrites w_bf)
    unsigned short* h_bf  = (unsigned short*)(ws);
    unsigned short* w_bf  = (unsigned short*)(ws + 8388608);
    unsigned short* d_bf  = (unsigned short*)(ws + 8388608);
    unsigned short* w1_bf = (unsigned short*)(ws + 12582912);

    cvt_inputs<<<2560, 256, 0, stream>>>(d, W1, d_bf, w1_bf, beq);

    gemm_bt_bf16<true ><<<dim3(32, 8), 256, 0, stream>>>(d_bf, w1_bf, b1, h_bf, 4096, 1024, 512,  beq, 0);
    gemm_bt_bf16<false><<<dim3(32, 6), 256, 0, stream>>>(h_bf, W2,    b2, w_bf, 4096, 760,  1024, beq, 1);

    admm_kernel<<<(BATCH + 2) / 3, 64, 0, stream>>>(w_bf, d_out, beq);
}

// Round 7
// 324.469 us; speedup vs baseline: 1.2746x; 1.0387x over previous
//
#include <hip/hip_runtime.h>

#define KG 20
#define N1 400
#define N2 760
#define BATCH 4096
#define NITER 50

typedef __attribute__((ext_vector_type(8))) short bf16x8;
typedef __attribute__((ext_vector_type(4))) float f32x4;

// Pure compiler barrier: orders the LDS ops in the instruction stream but emits
// NO s_waitcnt. Intra-wave DS ops execute in program order; the compiler still
// auto-inserts lgkmcnt waits before read results are consumed.
#define CBAR() asm volatile("" ::: "memory")

__device__ __forceinline__ float bf2f(unsigned short u) {
    unsigned int x = ((unsigned int)u) << 16;
    union { unsigned int i; float f; } c; c.i = x; return c.f;
}
__device__ __forceinline__ unsigned short f2bf(float f) {
    union { float f; unsigned int i; } c; c.f = f;
    unsigned int r = c.i + 0x7FFFu + ((c.i >> 16) & 1u);  // RNE
    return (unsigned short)(r >> 16);
}
// HW packed f32->bf16 (RNE, same result as f2bf for finite values).
__device__ __forceinline__ unsigned pk_bf16(float lo, float hi) {
    unsigned r;
    asm("v_cvt_pk_bf16_f32 %0, %1, %2" : "=v"(r) : "v"(lo), "v"(hi));
    return r;
}

// ---------------- compile-time DCT-II tables -----------------------------------
constexpr double CPI = 3.14159265358979323846;
constexpr double ccos(double x) {
    constexpr double TP = 6.28318530717958647692;
    long long k = (long long)(x / TP);
    double r = x - (double)k * TP;
    if (r > CPI)  r -= TP;
    if (r < -CPI) r += TP;
    double r2 = r * r, term = 1.0, s = 1.0;
    for (int n = 1; n <= 15; ++n) { term *= -r2 / ((2.0 * n - 1.0) * (2.0 * n)); s += term; }
    return s;
}
struct Tbl { float phi[10][20]; float lam[20]; };   // rows 0..9 only (fold symmetry)
constexpr Tbl mk_tbl() {
    Tbl t{};
    for (int i = 0; i < 10; ++i)
        for (int a = 0; a < 20; ++a) {
            double na = (a == 0) ? 0.22360679774997896964 : 0.31622776601683793320;
            t.phi[i][a] = (float)(na * ccos(CPI * (double)a * ((double)i + 0.5) / 20.0));
        }
    for (int a = 0; a < 20; ++a) t.lam[a] = (float)(2.0 - 2.0 * ccos(CPI * (double)a / 20.0));
    return t;
}
static constexpr Tbl TB = mk_tbl();

__device__ __forceinline__ int detect_flag(const float* beqf) {
    float v = beqf[0];
    return (v > 0.5f && v < 1.5f) ? 0 : 1;   // 0 = fp32 inputs, 1 = bf16 inputs
}

// ---------------- input pre-conversion (fp32 path only does real work) ---------
__global__ __launch_bounds__(256) void cvt_inputs(
        const void* __restrict__ src0, const void* __restrict__ src1,
        unsigned short* __restrict__ dst0, unsigned short* __restrict__ dst1,
        const float* __restrict__ beqf) {
    const int f = detect_flag(beqf);
    const int nv0 = (4096 * 512) / 4, nv1 = (1024 * 512) / 4;
    int idx = blockIdx.x * 256 + threadIdx.x;          // vec4 index
    if (idx >= nv0 + nv1) return;
    const void* s; unsigned short* dptr; int k;
    if (idx < nv0) { s = src0; dptr = dst0; k = idx; }
    else           { s = src1; dptr = dst1; k = idx - nv0; }
    if (f) {
        ((uint2*)dptr)[k] = ((const uint2*)s)[k];      // already bf16: 8B copy
    } else {
        float4 v = ((const float4*)s)[k];
        uint2 p; p.x = pk_bf16(v.x, v.y); p.y = pk_bf16(v.z, v.w);
        ((uint2*)dptr)[k] = p;
    }
}

// ---------------- MLP GEMM: 64x64 block, 4 blocks/CU (R7) ----------------------
// R6 post-mortem: all GEMM slabs fit in L2 (32MB agg) -> never HBM-bound. The
// regime is LATENCY-bound: 2-barrier K-loop exposes ~500-900cyc staging latency
// unless co-resident blocks interleave. Evidence: blocks/CU 2/1.5 (R4) -> 96us
// slice; 1/0.75 (R6) -> 110us. So shrink tiles: 64x64, 4 waves in 2x2, grid
// 1024 (gemm1, 4/CU) and 768 (gemm2, 3/CU). LDS 8.7KB.
template<bool LEAKY>
__global__ __launch_bounds__(256) void gemm_bt_bf16(
        const unsigned short* __restrict__ A,
        const void* __restrict__ B,
        const void* __restrict__ biasRaw,
        unsigned short* __restrict__ C,
        int M, int N, int K, const float* __restrict__ beqf, int bUseFlag) {
    __shared__ unsigned short As[64 * 34];
    __shared__ unsigned short Bs[64 * 34];
    const int f   = detect_flag(beqf);
    const int bBf = bUseFlag ? f : 1;
    const int tid  = threadIdx.x;
    const int m0   = blockIdx.x * 64;
    const int n0   = blockIdx.y * 64;
    const int wave = tid >> 6, lane = tid & 63;
    const int wm   = (wave & 1) * 32, wn = (wave >> 1) * 32;
    const int fr   = lane & 15;
    const int kc   = (lane >> 4) * 8;

    const int ra = tid >> 2, ca = (tid & 3) * 8;       // 64 rows x 32 cols, 8 shorts/thread
    const int rbg = (n0 + ra < N) ? (n0 + ra) : (N - 1);

    uint4 av, bv;
    auto load_tiles = [&](int k0) {
        size_t aoff = (size_t)(m0 + ra) * K + k0 + ca;
        av = *(const uint4*)&A[aoff];
        size_t boff = (size_t)rbg * K + k0 + ca;
        if (bBf) bv = *(const uint4*)&((const unsigned short*)B)[boff];
        else {
            const float* Bf = (const float*)B;
            float4 f0 = *(const float4*)&Bf[boff];
            float4 f1 = *(const float4*)&Bf[boff + 4];
            bv.x = pk_bf16(f0.x, f0.y);
            bv.y = pk_bf16(f0.z, f0.w);
            bv.z = pk_bf16(f1.x, f1.y);
            bv.w = pk_bf16(f1.z, f1.w);
        }
    };

    f32x4 acc[2][2];
#pragma unroll
    for (int a = 0; a < 2; a++)
#pragma unroll
        for (int b = 0; b < 2; b++) acc[a][b] = (f32x4){0.f, 0.f, 0.f, 0.f};

    load_tiles(0);
    for (int k0 = 0; k0 < K; k0 += 32) {
        *(uint4*)&As[ra * 34 + ca] = av;
        *(uint4*)&Bs[ra * 34 + ca] = bv;
        __syncthreads();

        int kn = (k0 + 32 < K) ? (k0 + 32) : k0;
        load_tiles(kn);

        bf16x8 af[2], bfm[2];
#pragma unroll
        for (int a = 0; a < 2; a++) af[a]  = *(const bf16x8*)&As[(wm + a * 16 + fr) * 34 + kc];
#pragma unroll
        for (int b = 0; b < 2; b++) bfm[b] = *(const bf16x8*)&Bs[(wn + b * 16 + fr) * 34 + kc];
#pragma unroll
        for (int a = 0; a < 2; a++)
#pragma unroll
            for (int b = 0; b < 2; b++)
                acc[a][b] = __builtin_amdgcn_mfma_f32_16x16x32_bf16(af[a], bfm[b], acc[a][b], 0, 0, 0);
        __syncthreads();
    }
#pragma unroll
    for (int a = 0; a < 2; a++)
#pragma unroll
        for (int b = 0; b < 2; b++) {
            int col = n0 + wn + b * 16 + (lane & 15);
            if (col < N) {
                float bs = f ? bf2f(((const unsigned short*)biasRaw)[col])
                             : ((const float*)biasRaw)[col];
#pragma unroll
                for (int r = 0; r < 4; r++) {
                    int row = m0 + wm + a * 16 + (lane >> 4) * 4 + r;
                    float v = acc[a][b][r] + bs;
                    if (LEAKY) v = v >= 0.f ? v : 0.1f * v;
                    C[(size_t)row * N + col] = f2bf(v);
                }
            }
        }
}

// ---------------- fused 50-iteration ADMM: 3 samples/wave (R4-exact, FROZEN) ---
// 5 rounds of probes (shfl, VGPR pin, SGPR pin, f2 packing) all regressed or
// were neutral. Equilibrium model: per-wave issue I ~ 240k cyc; 342 of 1024
// SIMDs carry 2 waves -> critical path ~ 2I ~ 202us; measured 227. f2 packing
// cut I/sample 34% but at 683 waves (1/SIMD) dependency bubbles B ~ 1.4I were
// fully exposed (R5: 28% VALUBusy) -> net loss. Do not touch.
#define SREG 448
__global__ __launch_bounds__(64, 1) void admm_kernel(
        const unsigned short* __restrict__ wglob,
        void* __restrict__ out, const float* __restrict__ beqf) {
    __shared__ float buf[3 * SREG];                // 5376 B

    const int lane = threadIdx.x;
    const int q    = (lane >= 40) ? 2 : (lane >= 20 ? 1 : 0);
    const int i    = lane - 20 * q;
    const int sample = blockIdx.x * 3 + q;
    const int flag = detect_flag(beqf);

    if (lane < 60 && sample < BATCH) {
        float* B = &buf[q * SREG];
        const size_t gb = (size_t)sample * N2;

        float wh[20], wv[20];
        if (i < 19) {
#pragma unroll
            for (int j = 0; j < 19; ++j) {
                wh[j] = bf2f(wglob[gb + 39 * i + 2 * j]);
                wv[j] = bf2f(wglob[gb + 39 * i + 2 * j + 1]);
            }
            wh[19] = 0.f;
            wv[19] = bf2f(wglob[gb + 39 * i + 38]);
        } else {
#pragma unroll
            for (int j = 0; j < 19; ++j) { wh[j] = bf2f(wglob[gb + 741 + j]); wv[j] = 0.f; }
            wh[19] = 0.f; wv[19] = 0.f;
        }

        float g[20];
        {
            float lamB = TB.lam[i];
#pragma unroll
            for (int a = 0; a < 20; ++a) g[a] = 1.f / (TB.lam[a] + lamB);
            if (i == 0) g[0] = 0.f;   // zero mode (0,0)
        }

        float sh[20], sv[20];
#pragma unroll
        for (int j = 0; j < 20; ++j) { sh[j] = 0.f; sv[j] = 0.f; }

        const int rup = (i > 0)  ? i - 1 : 0;
        const int rdn = (i < 19) ? i + 1 : i;

#pragma unroll 1
        for (int it = 0; it < NITER; ++it) {
            float vh[20], vv[20];
#pragma unroll
            for (int j = 0; j < 20; ++j) {
                vh[j] = fabsf(sh[j]) - wh[j];
                vv[j] = fabsf(sv[j]) - wv[j];
            }
#pragma unroll
            for (int j = 0; j < 20; j += 4)
                *(f32x4*)&B[20 * i + j] = (f32x4){vv[j], vv[j + 1], vv[j + 2], vv[j + 3]};
            CBAR();
            float vvUp[20];
#pragma unroll
            for (int j = 0; j < 20; j += 4) {
                f32x4 t = *(f32x4*)&B[20 * rup + j];
                vvUp[j] = t[0]; vvUp[j + 1] = t[1]; vvUp[j + 2] = t[2]; vvUp[j + 3] = t[3];
            }
            CBAR();
            float r[20];
#pragma unroll
            for (int j = 0; j < 20; ++j) {
                float acc = ((j < 19) ? vh[j] : 0.f) + vv[j];
                if (j > 0) acc -= vh[j - 1];
                acc -= (i > 0) ? vvUp[j] : 0.f;
                r[j] = acc;
            }
            r[0]  -= (i == 0)  ? 2.f : 0.f;
            r[19] += (i == 19) ? 2.f : 0.f;

            // ---- fold rows ----
            float e[10], o[10];
#pragma unroll
            for (int jj = 0; jj < 10; ++jj) { e[jj] = r[jj] + r[19 - jj]; o[jj] = r[jj] - r[19 - jj]; }
            // ---- T1[b] = folded row-DCT; transpose-1 store (stride 22) ----
#pragma unroll
            for (int b = 0; b < 20; ++b) {
                float a;
                if ((b & 1) == 0) {
                    a = e[0] * TB.phi[0][b];
#pragma unroll
                    for (int jj = 1; jj < 10; ++jj) a += e[jj] * TB.phi[jj][b];
                } else {
                    a = o[0] * TB.phi[0][b];
#pragma unroll
                    for (int jj = 1; jj < 10; ++jj) a += o[jj] * TB.phi[jj][b];
                }
                B[22 * b + i] = a;
            }
            CBAR();
            float t2[20];
#pragma unroll
            for (int k = 0; k < 20; k += 2) {
                float2 p = *(const float2*)&B[22 * i + k];
                t2[k] = p.x; t2[k + 1] = p.y;
            }
            CBAR();
            // ---- fold; U[a] = col-DCT; scale by g ----
            float e2[10], o2[10];
#pragma unroll
            for (int kk = 0; kk < 10; ++kk) { e2[kk] = t2[kk] + t2[19 - kk]; o2[kk] = t2[kk] - t2[19 - kk]; }
            float v2[20];
#pragma unroll
            for (int a = 0; a < 20; ++a) {
                float acc;
                if ((a & 1) == 0) {
                    acc = e2[0] * TB.phi[0][a];
#pragma unroll
                    for (int kk = 1; kk < 10; ++kk) acc += e2[kk] * TB.phi[kk][a];
                } else {
                    acc = o2[0] * TB.phi[0][a];
#pragma unroll
                    for (int kk = 1; kk < 10; ++kk) acc += o2[kk] * TB.phi[kk][a];
                }
                v2[a] = acc * g[a];
            }
            // ---- Y rows (output-pair folded); transpose-2 store ----
#pragma unroll
            for (int II = 0; II < 10; ++II) {
                float E = v2[0] * TB.phi[II][0];
#pragma unroll
                for (int m = 1; m < 10; ++m) E += v2[2 * m] * TB.phi[II][2 * m];
                float O = v2[1] * TB.phi[II][1];
#pragma unroll
                for (int m = 1; m < 10; ++m) O += v2[2 * m + 1] * TB.phi[II][2 * m + 1];
                B[22 * II + i]        = E + O;
                B[22 * (19 - II) + i] = E - O;
            }
            CBAR();
            float t3[20];
#pragma unroll
            for (int b = 0; b < 20; b += 2) {
                float2 p = *(const float2*)&B[22 * i + b];
                t3[b] = p.x; t3[b + 1] = p.y;
            }
            CBAR();
            // ---- nu rows (output-pair folded) ----
            float nu[20];
#pragma unroll
            for (int JJ = 0; JJ < 10; ++JJ) {
                float E = t3[0] * TB.phi[JJ][0];
#pragma unroll
                for (int m = 1; m < 10; ++m) E += t3[2 * m] * TB.phi[JJ][2 * m];
                float O = t3[1] * TB.phi[JJ][1];
#pragma unroll
                for (int m = 1; m < 10; ++m) O += t3[2 * m + 1] * TB.phi[JJ][2 * m + 1];
                nu[JJ]      = E + O;
                nu[19 - JJ] = E - O;
            }
#pragma unroll
            for (int j = 0; j < 20; j += 4)
                *(f32x4*)&B[20 * i + j] = (f32x4){nu[j], nu[j + 1], nu[j + 2], nu[j + 3]};
            CBAR();
            float nuDn[20];
#pragma unroll
            for (int j = 0; j < 20; j += 4) {
                f32x4 t = *(f32x4*)&B[20 * rdn + j];
                nuDn[j] = t[0]; nuDn[j + 1] = t[1]; nuDn[j + 2] = t[2]; nuDn[j + 3] = t[3];
            }
            CBAR();
#pragma unroll
            for (int j = 0; j < 20; ++j) {
                float xv = 0.5f * (vv[j] - nu[j] + nuDn[j]);
                sv[j] = xv + fminf(sv[j], 0.f);
                float xh = 0.f;
                if (j < 19) {
                    xh = 0.5f * (vh[j] - nu[j] + nu[j + 1]);
                    sh[j] = xh + fminf(sh[j], 0.f);
                }
                if (it == NITER - 1) {
                    if (i < 19) {
                        if (j < 19) {
                            if (flag) {
                                ((unsigned short*)out)[gb + 39 * i + 2 * j]     = f2bf(xh);
                                ((unsigned short*)out)[gb + 39 * i + 2 * j + 1] = f2bf(xv);
                            } else {
                                ((float*)out)[gb + 39 * i + 2 * j]     = xh;
                                ((float*)out)[gb + 39 * i + 2 * j + 1] = xv;
                            }
                        } else {
                            if (flag) ((unsigned short*)out)[gb + 39 * i + 38] = f2bf(xv);
                            else      ((float*)out)[gb + 39 * i + 38] = xv;
                        }
                    } else if (j < 19) {
                        if (flag) ((unsigned short*)out)[gb + 741 + j] = f2bf(xh);
                        else      ((float*)out)[gb + 741 + j] = xh;
                    }
                }
            }
        }
    }
}

extern "C" void kernel_launch(void* const* d_in, const int* in_sizes, int n_in,
                              void* d_out, int out_size, void* d_ws, size_t ws_size,
                              hipStream_t stream) {
    (void)in_sizes; (void)n_in; (void)out_size; (void)ws_size;
    const void*  d   = d_in[0];
    const void*  W1  = d_in[1];
    const void*  b1  = d_in[2];
    const void*  W2  = d_in[3];
    const void*  b2  = d_in[4];
    const float* beq = (const float*)d_in[6];   // A (d_in[5]) unused: closed-form

    char* ws = (char*)d_ws;
    // Layout (total 14614528 B):
    //   h_bf  @ 0        : 4096x1024 bf16 = 8388608 B   (gemm1 out, gemm2 in)
    //   w_bf  @ 8388608  : 4096x760  bf16 = 6225920 B   (gemm2 out, admm in)
    //   d_bf  @ 8388608  : 4096x512  bf16 = 4194304 B   (aliases w_bf: dead
    //   w1_bf @ 12582912 : 1024x512  bf16 = 1048576 B    by the time gemm2
    //                                                    overwrites w_bf)
    unsigned short* h_bf  = (unsigned short*)(ws);
    unsigned short* w_bf  = (unsigned short*)(ws + 8388608);
    unsigned short* d_bf  = (unsigned short*)(ws + 8388608);
    unsigned short* w1_bf = (unsigned short*)(ws + 12582912);

    cvt_inputs<<<2560, 256, 0, stream>>>(d, W1, d_bf, w1_bf, beq);

    gemm_bt_bf16<true ><<<dim3(64, 16), 256, 0, stream>>>(d_bf, w1_bf, b1, h_bf, 4096, 1024, 512,  beq, 0);
    gemm_bt_bf16<false><<<dim3(64, 12), 256, 0, stream>>>(h_bf, W2,    b2, w_bf, 4096, 760,  1024, beq, 1);

    admm_kernel<<<(BATCH + 2) / 3, 64, 0, stream>>>(w_bf, d_out, beq);
}